// Round 2
// baseline (81.686 us; speedup 1.0000x reference)
//
#include <hip/hip_runtime.h>

namespace {
constexpr int Bc  = 4;
constexpr int Lc  = 4096;
constexpr int Dc  = 2048;
constexpr int Gc  = 32;
constexpr int GSc = 64;
constexpr float EPSc = 1e-5f;
constexpr long long NY = (long long)Bc * Lc * Dc;       // 33,554,432
constexpr long long NM = (long long)Bc * Gc * Lc;       // 524,288 per-array
}

// K1: per-(b,g,t) group means. Each thread loads float4; 16 lanes cover one
// 64-element group; shfl_xor tree-reduce within the 16-lane segment.
__global__ __launch_bounds__(256) void k_group_means(const float* __restrict__ x,
                                                     float* __restrict__ m) {
    int tid = threadIdx.x;
    long long base = (long long)blockIdx.x * 1024 + (long long)tid * 4;
    float4 v = *reinterpret_cast<const float4*>(x + base);
    float s = v.x + v.y + v.z + v.w;
    s += __shfl_xor(s, 1);
    s += __shfl_xor(s, 2);
    s += __shfl_xor(s, 4);
    s += __shfl_xor(s, 8);
    if ((tid & 15) == 0) {
        int d = (int)(base % Dc);
        long long rt = base / Dc;
        int t = (int)(rt % Lc);
        int b = (int)(rt / Lc);
        int g = d >> 6;  // GSc == 64
        m[(long long)(b * Gc + g) * Lc + t] = s * (1.0f / GSc);
    }
}

// K2: one block per (b,g). Block-scan of (m, m^2, validcount) over L in fp64,
// emit mean_t / rstd_t per timestep + final count/mean/var outputs.
// Welford-as-prefix-scan (Chan's merge), exactly matching the reference's
// max(count,1) quirk via M2_0 = prev_var * max(c0,1).
__global__ __launch_bounds__(256) void k_scan(const float* __restrict__ m,
                                              const int* __restrict__ prev_count,
                                              const float* __restrict__ prev_mean,
                                              const float* __restrict__ prev_var,
                                              const int* __restrict__ mask,   // bool pushed as int32
                                              float* __restrict__ meanArr,
                                              float* __restrict__ rstdArr,
                                              float* __restrict__ out_count,
                                              float* __restrict__ out_mean,
                                              float* __restrict__ out_var) {
    int bg = blockIdx.x;
    int b = bg / Gc;
    int g = bg % Gc;
    int tid = threadIdx.x;
    const float* mrow = m + (long long)bg * Lc;
    const int* mk = mask + (long long)b * Lc;

    const int PT = Lc / 256;  // 16 timesteps per thread
    int t0 = tid * PT;

    float vals[16];
    unsigned char vm[16];
    double ls1 = 0.0, ls2 = 0.0;
    int lc = 0;
    for (int j = 0; j < PT; ++j) {
        float v = mrow[t0 + j];
        unsigned char q = (mk[t0 + j] != 0) ? 1 : 0;
        vals[j] = v; vm[j] = q;
        if (q) { ls1 += v; ls2 += (double)v * v; ++lc; }
    }

    __shared__ double sh1[256];
    __shared__ double sh2[256];
    __shared__ int    shc[256];
    sh1[tid] = ls1; sh2[tid] = ls2; shc[tid] = lc;
    __syncthreads();
    for (int off = 1; off < 256; off <<= 1) {
        double a1 = 0.0, a2 = 0.0; int ac = 0;
        if (tid >= off) { a1 = sh1[tid - off]; a2 = sh2[tid - off]; ac = shc[tid - off]; }
        __syncthreads();
        sh1[tid] += a1; sh2[tid] += a2; shc[tid] += ac;
        __syncthreads();
    }
    double run1 = sh1[tid] - ls1;   // exclusive prefixes
    double run2 = sh2[tid] - ls2;
    int    runc = shc[tid] - lc;

    double c0    = (double)prev_count[b];
    double mean0 = (double)prev_mean[bg];
    double M2_0  = (double)prev_var[bg] * fmax(c0, 1.0);

    for (int j = 0; j < PT; ++j) {
        if (vm[j]) {
            run1 += vals[j];
            run2 += (double)vals[j] * vals[j];
            ++runc;
        }
        double cv    = (double)runc;
        double ctot  = c0 + cv;
        double csafe = fmax(ctot, 1.0);
        double meanT = (c0 * mean0 + run1) / csafe;
        double M2 = M2_0;
        if (runc > 0) {
            M2 += run2 - run1 * run1 / cv;          // batch M2
            double dd = run1 / cv - mean0;
            M2 += dd * dd * c0 * cv / csafe;        // Chan merge term
        }
        double varT = M2 / csafe;
        long long o = (long long)bg * Lc + t0 + j;
        meanArr[o] = (float)meanT;
        rstdArr[o] = (float)(1.0 / sqrt(varT + (double)EPSc));
    }

    if (tid == 255) {
        double cv    = (double)runc;
        double ctot  = c0 + cv;
        double csafe = fmax(ctot, 1.0);
        double meanF = (c0 * mean0 + run1) / csafe;
        double M2 = M2_0;
        if (runc > 0) {
            M2 += run2 - run1 * run1 / cv;
            double dd = run1 / cv - mean0;
            M2 += dd * dd * c0 * cv / csafe;
        }
        double varF = M2 / csafe;
        if (g == 0) out_count[b] = (float)ctot;  // buffer read back as float32
        out_mean[bg] = (float)meanF;
        out_var[bg]  = (float)varF;
    }
}

// K3: elementwise normalize, float4-vectorized, grid-stride.
__global__ __launch_bounds__(256) void k_norm(const float* __restrict__ x,
                                              const float* __restrict__ meanArr,
                                              const float* __restrict__ rstdArr,
                                              const float* __restrict__ w,
                                              const float* __restrict__ bias,
                                              float* __restrict__ y) {
    long long i = (long long)blockIdx.x * blockDim.x + threadIdx.x;
    long long stride = (long long)gridDim.x * blockDim.x;
    const long long n4 = NY / 4;
    for (; i < n4; i += stride) {
        long long fi = i * 4;
        int d = (int)(fi % Dc);
        long long rt = fi / Dc;
        int t = (int)(rt % Lc);
        int b = (int)(rt / Lc);
        int g = d >> 6;
        long long o = (long long)(b * Gc + g) * Lc + t;
        float mean = meanArr[o];
        float rstd = rstdArr[o];
        float4 xv = *reinterpret_cast<const float4*>(x + fi);
        float4 wv = *reinterpret_cast<const float4*>(w + d);
        float4 bv = *reinterpret_cast<const float4*>(bias + d);
        float4 yv;
        yv.x = (xv.x - mean) * rstd * wv.x + bv.x;
        yv.y = (xv.y - mean) * rstd * wv.y + bv.y;
        yv.z = (xv.z - mean) * rstd * wv.z + bv.z;
        yv.w = (xv.w - mean) * rstd * wv.w + bv.w;
        *reinterpret_cast<float4*>(y + fi) = yv;
    }
}

extern "C" void kernel_launch(void* const* d_in, const int* in_sizes, int n_in,
                              void* d_out, int out_size, void* d_ws, size_t ws_size,
                              hipStream_t stream) {
    const float* x            = (const float*)d_in[0];
    const int* prev_count     = (const int*)d_in[1];
    const float* prev_mean    = (const float*)d_in[2];
    const float* prev_var     = (const float*)d_in[3];
    const int* mask           = (const int*)d_in[4];   // bool -> int32 per harness
    const float* weight       = (const float*)d_in[5];
    const float* bias         = (const float*)d_in[6];

    float* out       = (float*)d_out;
    float* y         = out;
    float* out_count = out + NY;
    float* out_mean  = out_count + Bc;
    float* out_var   = out_mean + (long long)Bc * Gc;

    float* m       = (float*)d_ws;
    float* meanArr = m + NM;
    float* rstdArr = meanArr + NM;

    // K1: 33,554,432 floats / 1024 per block
    k_group_means<<<(int)(NY / 1024), 256, 0, stream>>>(x, m);
    // K2: one block per (b,g)
    k_scan<<<Bc * Gc, 256, 0, stream>>>(m, prev_count, prev_mean, prev_var, mask,
                                        meanArr, rstdArr, out_count, out_mean, out_var);
    // K3: grid-stride elementwise
    k_norm<<<8192, 256, 0, stream>>>(x, meanArr, rstdArr, weight, bias, y);
}

// Round 4
// 76.400 us; speedup vs baseline: 1.0692x; 1.0692x over previous
//
#include <hip/hip_runtime.h>

namespace {
constexpr int Bc  = 4;
constexpr int Lc  = 4096;
constexpr int Dc  = 2048;
constexpr int Gc  = 32;
constexpr int GSc = 64;
constexpr float EPSc = 1e-5f;
constexpr long long NY = (long long)Bc * Lc * Dc;       // 33,554,432
constexpr long long NM = (long long)Bc * Gc * Lc;       // 524,288 per-array
typedef float vfloat4 __attribute__((ext_vector_type(4)));
}

// K1: per-(b,g,t) group means. Each thread loads float4; 16 lanes cover one
// 64-element group; shfl_xor tree-reduce within the 16-lane segment.
__global__ __launch_bounds__(256) void k_group_means(const float* __restrict__ x,
                                                     float* __restrict__ m) {
    int tid = threadIdx.x;
    long long base = (long long)blockIdx.x * 1024 + (long long)tid * 4;
    float4 v = *reinterpret_cast<const float4*>(x + base);
    float s = v.x + v.y + v.z + v.w;
    s += __shfl_xor(s, 1);
    s += __shfl_xor(s, 2);
    s += __shfl_xor(s, 4);
    s += __shfl_xor(s, 8);
    if ((tid & 15) == 0) {
        int d = (int)(base % Dc);
        long long rt = base / Dc;
        int t = (int)(rt % Lc);
        int b = (int)(rt / Lc);
        int g = d >> 6;  // GSc == 64
        m[(long long)(b * Gc + g) * Lc + t] = s * (1.0f / GSc);
    }
}

// K2: one block per (b,g). Block-scan of (m, m^2, validcount) over L.
// Prefix sums in fp64 (accuracy); per-element finalize in fp32 with
// single-instruction rcp/rsq (error ~1e-7, threshold 81.92 -> huge headroom).
// Welford-as-prefix-scan (Chan's merge), matching the reference's
// max(count,1) quirk via M2_0 = prev_var * max(c0,1).
__global__ __launch_bounds__(256) void k_scan(const float* __restrict__ m,
                                              const int* __restrict__ prev_count,
                                              const float* __restrict__ prev_mean,
                                              const float* __restrict__ prev_var,
                                              const int* __restrict__ mask,   // bool pushed as int32
                                              float* __restrict__ meanArr,
                                              float* __restrict__ rstdArr,
                                              float* __restrict__ out_count,
                                              float* __restrict__ out_mean,
                                              float* __restrict__ out_var) {
    int bg = blockIdx.x;
    int b = bg / Gc;
    int g = bg % Gc;
    int tid = threadIdx.x;
    const float* mrow = m + (long long)bg * Lc;
    const int* mk = mask + (long long)b * Lc;

    const int PT = Lc / 256;  // 16 timesteps per thread
    int t0 = tid * PT;

    float vals[16];
    int vm[16];
    // vectorized loads: 4x float4 + 4x int4
    {
        const float4* mv4 = reinterpret_cast<const float4*>(mrow + t0);
        const int4*   kv4 = reinterpret_cast<const int4*>(mk + t0);
        #pragma unroll
        for (int q = 0; q < 4; ++q) {
            float4 fv = mv4[q];
            int4   iv = kv4[q];
            vals[q*4+0] = fv.x; vals[q*4+1] = fv.y; vals[q*4+2] = fv.z; vals[q*4+3] = fv.w;
            vm[q*4+0] = iv.x;   vm[q*4+1] = iv.y;   vm[q*4+2] = iv.z;   vm[q*4+3] = iv.w;
        }
    }

    double ls1 = 0.0, ls2 = 0.0;
    int lc = 0;
    #pragma unroll
    for (int j = 0; j < PT; ++j) {
        if (vm[j]) { ls1 += vals[j]; ls2 += (double)vals[j] * vals[j]; ++lc; }
    }

    __shared__ double sh1[256];
    __shared__ double sh2[256];
    __shared__ int    shc[256];
    sh1[tid] = ls1; sh2[tid] = ls2; shc[tid] = lc;
    __syncthreads();
    for (int off = 1; off < 256; off <<= 1) {
        double a1 = 0.0, a2 = 0.0; int ac = 0;
        if (tid >= off) { a1 = sh1[tid - off]; a2 = sh2[tid - off]; ac = shc[tid - off]; }
        __syncthreads();
        sh1[tid] += a1; sh2[tid] += a2; shc[tid] += ac;
        __syncthreads();
    }
    double run1 = sh1[tid] - ls1;   // exclusive prefixes
    double run2 = sh2[tid] - ls2;
    int    runc = shc[tid] - lc;

    double c0    = (double)prev_count[b];
    double mean0 = (double)prev_mean[bg];
    double M2_0  = (double)prev_var[bg] * fmax(c0, 1.0);

    const float c0f    = (float)c0;
    const float mean0f = (float)mean0;
    const float M2_0f  = (float)M2_0;

    float omean[16], orstd[16];
    #pragma unroll
    for (int j = 0; j < PT; ++j) {
        if (vm[j]) {
            run1 += vals[j];
            run2 += (double)vals[j] * vals[j];
            ++runc;
        }
        float run1f = (float)run1;
        float run2f = (float)run2;
        float cv    = (float)runc;
        float ctot  = c0f + cv;
        float csafe = fmaxf(ctot, 1.0f);
        float invcsafe = __builtin_amdgcn_rcpf(csafe);
        float meanT = fmaf(c0f, mean0f, run1f) * invcsafe;
        float M2 = M2_0f;
        if (runc > 0) {
            float invcv = __builtin_amdgcn_rcpf(cv);
            M2 += run2f - run1f * run1f * invcv;            // batch M2
            float dd = run1f * invcv - mean0f;
            M2 += dd * dd * c0f * cv * invcsafe;            // Chan merge term
        }
        float varT = M2 * invcsafe;
        omean[j] = meanT;
        orstd[j] = __builtin_amdgcn_rsqf(varT + EPSc);
    }
    // vectorized stores
    {
        float4* mo = reinterpret_cast<float4*>(meanArr + (long long)bg * Lc + t0);
        float4* ro = reinterpret_cast<float4*>(rstdArr + (long long)bg * Lc + t0);
        #pragma unroll
        for (int q = 0; q < 4; ++q) {
            mo[q] = make_float4(omean[q*4+0], omean[q*4+1], omean[q*4+2], omean[q*4+3]);
            ro[q] = make_float4(orstd[q*4+0], orstd[q*4+1], orstd[q*4+2], orstd[q*4+3]);
        }
    }

    if (tid == 255) {
        // final carry outputs in fp64 (once per block, cost negligible)
        double cv    = (double)runc;
        double ctot  = c0 + cv;
        double csafe = fmax(ctot, 1.0);
        double meanF = (c0 * mean0 + run1) / csafe;
        double M2 = M2_0;
        if (runc > 0) {
            M2 += run2 - run1 * run1 / cv;
            double dd = run1 / cv - mean0;
            M2 += dd * dd * c0 * cv / csafe;
        }
        double varF = M2 / csafe;
        if (g == 0) out_count[b] = (float)ctot;  // buffer read back as float32
        out_mean[bg] = (float)meanF;
        out_var[bg]  = (float)varF;
    }
}

// K3: elementwise normalize, float4-vectorized, nontemporal y-stores so the
// 128 MiB x stays resident in the 256 MiB Infinity Cache across replays.
__global__ __launch_bounds__(256) void k_norm(const float* __restrict__ x,
                                              const float* __restrict__ meanArr,
                                              const float* __restrict__ rstdArr,
                                              const float* __restrict__ w,
                                              const float* __restrict__ bias,
                                              float* __restrict__ y) {
    const int n4 = (int)(NY / 4);            // 2^23, fits int32
    int stride = gridDim.x * blockDim.x;     // 2^21
    for (int i = blockIdx.x * blockDim.x + threadIdx.x; i < n4; i += stride) {
        int d4 = i & (Dc / 4 - 1);           // 0..511
        int rt = i >> 9;                     // (b*Lc + t)
        int t  = rt & (Lc - 1);
        int b  = rt >> 12;
        int g  = d4 >> 4;                    // 16 float4s per 64-elem group
        int o  = (b * Gc + g) * Lc + t;
        float mean = meanArr[o];
        float rstd = rstdArr[o];
        int d = d4 * 4;
        float4 xv = *reinterpret_cast<const float4*>(x + (long long)i * 4);
        float4 wv = *reinterpret_cast<const float4*>(w + d);
        float4 bv = *reinterpret_cast<const float4*>(bias + d);
        vfloat4 yv;
        yv.x = (xv.x - mean) * rstd * wv.x + bv.x;
        yv.y = (xv.y - mean) * rstd * wv.y + bv.y;
        yv.z = (xv.z - mean) * rstd * wv.z + bv.z;
        yv.w = (xv.w - mean) * rstd * wv.w + bv.w;
        __builtin_nontemporal_store(yv, reinterpret_cast<vfloat4*>(y + (long long)i * 4));
    }
}

extern "C" void kernel_launch(void* const* d_in, const int* in_sizes, int n_in,
                              void* d_out, int out_size, void* d_ws, size_t ws_size,
                              hipStream_t stream) {
    const float* x            = (const float*)d_in[0];
    const int* prev_count     = (const int*)d_in[1];
    const float* prev_mean    = (const float*)d_in[2];
    const float* prev_var     = (const float*)d_in[3];
    const int* mask           = (const int*)d_in[4];   // bool -> int32 per harness
    const float* weight       = (const float*)d_in[5];
    const float* bias         = (const float*)d_in[6];

    float* out       = (float*)d_out;
    float* y         = out;
    float* out_count = out + NY;
    float* out_mean  = out_count + Bc;
    float* out_var   = out_mean + (long long)Bc * Gc;

    float* m       = (float*)d_ws;
    float* meanArr = m + NM;
    float* rstdArr = meanArr + NM;

    // K1: 33,554,432 floats / 1024 per block
    k_group_means<<<(int)(NY / 1024), 256, 0, stream>>>(x, m);
    // K2: one block per (b,g)
    k_scan<<<Bc * Gc, 256, 0, stream>>>(m, prev_count, prev_mean, prev_var, mask,
                                        meanArr, rstdArr, out_count, out_mean, out_var);
    // K3: grid-stride elementwise, NT stores
    k_norm<<<8192, 256, 0, stream>>>(x, meanArr, rstdArr, weight, bias, y);
}

// Round 5
// 66.228 us; speedup vs baseline: 1.2334x; 1.1536x over previous
//
#include <hip/hip_runtime.h>

namespace {
constexpr int Bc  = 4;
constexpr int Lc  = 4096;
constexpr int Dc  = 2048;
constexpr int Gc  = 32;
constexpr int GSc = 64;
constexpr int CHUNKS = 8;
constexpr int CT = Lc / CHUNKS;          // 512 timesteps per chunk
constexpr float EPSc = 1e-5f;
constexpr long long NY = (long long)Bc * Lc * Dc;   // 33,554,432
constexpr long long NM = (long long)Bc * Gc * Lc;   // 524,288
typedef float vfloat4 __attribute__((ext_vector_type(4)));
}

// kA: block = (bg, chunk). Reads its 512x64 x-slice (the ONLY full HBM read
// of x), computes 512 group means -> gmeans, and the chunk's masked fp64
// (S1, S2, count) totals -> part.
__global__ __launch_bounds__(256) void kA(const float* __restrict__ x,
                                          const int* __restrict__ mask,
                                          float* __restrict__ gmeans,
                                          double* __restrict__ part) {
    int blk = blockIdx.x, chunk = blk & (CHUNKS - 1), bg = blk >> 3;
    int b = bg >> 5, g = bg & (Gc - 1);
    int tid = threadIdx.x, rowi = tid >> 4, col4 = tid & 15;
    const long long xbase = ((long long)b * Lc + (long long)chunk * CT) * Dc + (long long)g * GSc;

    __shared__ float sm[CT];
    for (int it = 0; it < CT / 16; ++it) {       // 16 rows per iter, 32 iters
        int r = it * 16 + rowi;
        const float4 xv = *reinterpret_cast<const float4*>(x + xbase + (long long)r * Dc + col4 * 4);
        float s = xv.x + xv.y + xv.z + xv.w;
        s += __shfl_xor(s, 1);
        s += __shfl_xor(s, 2);
        s += __shfl_xor(s, 4);
        s += __shfl_xor(s, 8);
        if (col4 == 0) sm[r] = s * (1.0f / GSc);
    }
    __syncthreads();

    // means -> global (2 KB contiguous per block)
    if (tid < CT / 4) {
        float4 mv = *reinterpret_cast<float4*>(sm + tid * 4);
        *reinterpret_cast<float4*>(gmeans + (long long)bg * Lc + chunk * CT + tid * 4) = mv;
    }

    // masked fp64 partial totals (2 elems/thread, LDS tree reduce)
    const int* mrow = mask + (long long)b * Lc + chunk * CT;
    float v0 = sm[tid * 2], v1 = sm[tid * 2 + 1];
    int q0 = mrow[tid * 2], q1 = mrow[tid * 2 + 1];
    double ls1 = 0.0, ls2 = 0.0; int lc = 0;
    if (q0) { ls1 += v0; ls2 += (double)v0 * v0; ++lc; }
    if (q1) { ls1 += v1; ls2 += (double)v1 * v1; ++lc; }
    __shared__ double r1[256], r2[256];
    __shared__ int rc[256];
    r1[tid] = ls1; r2[tid] = ls2; rc[tid] = lc;
    __syncthreads();
    for (int off = 128; off > 0; off >>= 1) {
        if (tid < off) { r1[tid] += r1[tid + off]; r2[tid] += r2[tid + off]; rc[tid] += rc[tid + off]; }
        __syncthreads();
    }
    if (tid == 0) {
        double* p = part + ((long long)bg * CHUNKS + chunk) * 3;
        p[0] = r1[0]; p[1] = r2[0]; p[2] = (double)rc[0];
    }
}

// kB: block = (bg, chunk). Rebuilds the in-chunk prefix scan from gmeans
// (L2-hot), adds the carry from part, finalizes mean/rstd in fp32 (rcp/rsq),
// then re-reads x (L3-hot from kA) and writes y with NT stores.
__global__ __launch_bounds__(256) void kB(const float* __restrict__ x,
                                          const float* __restrict__ gmeans,
                                          const double* __restrict__ part,
                                          const int* __restrict__ prev_count,
                                          const float* __restrict__ prev_mean,
                                          const float* __restrict__ prev_var,
                                          const int* __restrict__ mask,
                                          const float* __restrict__ w,
                                          const float* __restrict__ bias,
                                          float* __restrict__ y,
                                          float* __restrict__ out_count,
                                          float* __restrict__ out_mean,
                                          float* __restrict__ out_var) {
    int blk = blockIdx.x, chunk = blk & (CHUNKS - 1), bg = blk >> 3;
    int b = bg >> 5, g = bg & (Gc - 1);
    int tid = threadIdx.x, rowi = tid >> 4, col4 = tid & 15;

    __shared__ float smean[CT], srstd[CT];
    __shared__ double s1[256], s2[256];
    __shared__ int sc[256];

    const float* mrow = gmeans + (long long)bg * Lc + chunk * CT;
    const int* krow = mask + (long long)b * Lc + chunk * CT;
    float v0 = mrow[tid * 2], v1 = mrow[tid * 2 + 1];
    int q0 = krow[tid * 2], q1 = krow[tid * 2 + 1];
    double ls1 = 0.0, ls2 = 0.0; int lc = 0;
    if (q0) { ls1 += v0; ls2 += (double)v0 * v0; ++lc; }
    if (q1) { ls1 += v1; ls2 += (double)v1 * v1; ++lc; }
    s1[tid] = ls1; s2[tid] = ls2; sc[tid] = lc;
    __syncthreads();
    for (int off = 1; off < 256; off <<= 1) {
        double a1 = 0.0, a2 = 0.0; int ac = 0;
        if (tid >= off) { a1 = s1[tid - off]; a2 = s2[tid - off]; ac = sc[tid - off]; }
        __syncthreads();
        s1[tid] += a1; s2[tid] += a2; sc[tid] += ac;
        __syncthreads();
    }
    double ex1 = s1[tid] - ls1, ex2 = s2[tid] - ls2;
    int exc = sc[tid] - lc;

    // carry over previous chunks (8x3 doubles, L2-hit, redundant per thread)
    double c1 = 0.0, c2 = 0.0, ccnt = 0.0;
    const double* pb = part + (long long)bg * CHUNKS * 3;
    for (int c = 0; c < chunk; ++c) { c1 += pb[c * 3]; c2 += pb[c * 3 + 1]; ccnt += pb[c * 3 + 2]; }

    double c0    = (double)prev_count[b];
    double mean0 = (double)prev_mean[bg];
    double M2_0  = (double)prev_var[bg] * fmax(c0, 1.0);
    const float c0f = (float)c0, mean0f = (float)mean0, M2_0f = (float)M2_0;

    double run1 = c1 + ex1, run2 = c2 + ex2, runc = ccnt + (double)exc;
    #pragma unroll
    for (int e = 0; e < 2; ++e) {
        float vv = e ? v1 : v0;
        int qq = e ? q1 : q0;
        if (qq) { run1 += vv; run2 += (double)vv * vv; runc += 1.0; }
        float run1f = (float)run1, run2f = (float)run2, cv = (float)runc;
        float ctot = c0f + cv, csafe = fmaxf(ctot, 1.0f);
        float invcs = __builtin_amdgcn_rcpf(csafe);
        float meanT = fmaf(c0f, mean0f, run1f) * invcs;
        float M2 = M2_0f;
        if (runc > 0.0) {
            float invcv = __builtin_amdgcn_rcpf(cv);
            M2 += run2f - run1f * run1f * invcv;
            float dd = run1f * invcv - mean0f;
            M2 += dd * dd * c0f * cv * invcs;
        }
        float varT = M2 * invcs;
        smean[tid * 2 + e] = meanT;
        srstd[tid * 2 + e] = __builtin_amdgcn_rsqf(varT + EPSc);
    }

    if (chunk == CHUNKS - 1 && tid == 255) {
        // final carry outputs in fp64
        double S1 = c1 + s1[255], S2 = c2 + s2[255], cv = ccnt + (double)sc[255];
        double ctot = c0 + cv, csafe = fmax(ctot, 1.0);
        double meanF = (c0 * mean0 + S1) / csafe;
        double M2 = M2_0;
        if (cv > 0.0) {
            M2 += S2 - S1 * S1 / cv;
            double dd = S1 / cv - mean0;
            M2 += dd * dd * c0 * cv / csafe;
        }
        double varF = M2 / csafe;
        if (g == 0) out_count[b] = (float)ctot;   // buffer read back as float32
        out_mean[bg] = (float)meanF;
        out_var[bg]  = (float)varF;
    }
    __syncthreads();

    // normalize: re-read x (L3-hot), NT-store y
    const long long xbase = ((long long)b * Lc + (long long)chunk * CT) * Dc + (long long)g * GSc;
    float4 wv = *reinterpret_cast<const float4*>(w + g * GSc + col4 * 4);
    float4 bvv = *reinterpret_cast<const float4*>(bias + g * GSc + col4 * 4);
    for (int it = 0; it < CT / 16; ++it) {
        int r = it * 16 + rowi;
        float mean = smean[r];                    // 16-lane broadcast, conflict-free
        float rstd = srstd[r];
        const float4 xv = *reinterpret_cast<const float4*>(x + xbase + (long long)r * Dc + col4 * 4);
        vfloat4 yv;
        yv.x = (xv.x - mean) * rstd * wv.x + bvv.x;
        yv.y = (xv.y - mean) * rstd * wv.y + bvv.y;
        yv.z = (xv.z - mean) * rstd * wv.z + bvv.z;
        yv.w = (xv.w - mean) * rstd * wv.w + bvv.w;
        __builtin_nontemporal_store(yv, reinterpret_cast<vfloat4*>(y + xbase + (long long)r * Dc + col4 * 4));
    }
}

extern "C" void kernel_launch(void* const* d_in, const int* in_sizes, int n_in,
                              void* d_out, int out_size, void* d_ws, size_t ws_size,
                              hipStream_t stream) {
    const float* x         = (const float*)d_in[0];
    const int* prev_count  = (const int*)d_in[1];
    const float* prev_mean = (const float*)d_in[2];
    const float* prev_var  = (const float*)d_in[3];
    const int* mask        = (const int*)d_in[4];   // bool -> int32 per harness
    const float* weight    = (const float*)d_in[5];
    const float* bias      = (const float*)d_in[6];

    float* out       = (float*)d_out;
    float* y         = out;
    float* out_count = out + NY;
    float* out_mean  = out_count + Bc;
    float* out_var   = out_mean + (long long)Bc * Gc;

    float* gmeans = (float*)d_ws;                   // NM floats = 2 MB
    double* part  = (double*)((char*)d_ws + NM * sizeof(float));  // 24 KB, 8B-aligned

    const int grid = Bc * Gc * CHUNKS;              // 1024 blocks
    kA<<<grid, 256, 0, stream>>>(x, mask, gmeans, part);
    kB<<<grid, 256, 0, stream>>>(x, gmeans, part, prev_count, prev_mean, prev_var,
                                 mask, weight, bias, y, out_count, out_mean, out_var);
}